// Round 8
// baseline (271.839 us; speedup 1.0000x reference)
//
#include <hip/hip_runtime.h>
#include <hip/hip_bf16.h>
#include <math.h>

#define BATCH 8
#define SEQ 384
#define DIM 768
#define NH 12
#define DH 64
#define NPOS 767
#define POS_OFF 128
#define NTOK (BATCH * SEQ)
#define QKN 1536
#define QKVN 2304
#define PN 1536

typedef __attribute__((ext_vector_type(8))) short short8;
typedef __attribute__((ext_vector_type(4))) float floatx4;
typedef unsigned int u32;

__device__ __forceinline__ ushort f2bf(float f) {
    __hip_bfloat16 h = __float2bfloat16(f);
    return *reinterpret_cast<ushort*>(&h);
}
__device__ __forceinline__ float bf2f(ushort u) {
    u32 x = ((u32)u) << 16;
    float f; __builtin_memcpy(&f, &x, 4); return f;
}

// async global->LDS, 16B per lane; lds dest = wave-uniform base + lane*16
__device__ __forceinline__ void gld16(const ushort* g, ushort* l) {
    __builtin_amdgcn_global_load_lds(
        (const __attribute__((address_space(1))) u32*)g,
        (__attribute__((address_space(3))) u32*)l, 16, 0, 0);
}

#define MFMA __builtin_amdgcn_mfma_f32_16x16x32_bf16

// ---------- prep: weight transposes (z<6) + row converts (z==6) -----------
__global__ __launch_bounds__(256) void prep(
    const float* W0, const float* W1, const float* W2,
    const float* W3, const float* W4, const float* W5,
    const float* x, const float* rpe,
    ushort* __restrict__ wsT, ushort* __restrict__ xb, ushort* __restrict__ rpeb)
{
    const int tid = threadIdx.x;
    if (blockIdx.z < 6) {
        __shared__ float t[64][65];
        const float* srcs[6] = {W0, W1, W2, W3, W4, W5};
        const float* in = srcs[blockIdx.z];
        ushort* out = wsT + (size_t)blockIdx.z * DIM * DIM;
        const int r0 = blockIdx.y * 64, c0 = blockIdx.x * 64;
        for (int p = 0; p < 16; ++p) {
            int e = tid + p * 256, i = e >> 6, j = e & 63;
            t[i][j] = in[(size_t)(r0 + i) * DIM + c0 + j];
        }
        __syncthreads();
        for (int p = 0; p < 16; ++p) {
            int e = tid + p * 256, i = e >> 6, j = e & 63;
            out[(size_t)(c0 + i) * DIM + r0 + j] = f2bf(t[j][i]);
        }
    } else {
        const int n4x = NTOK * DIM / 4;
        const int n4p = NPOS * DIM / 4;
        const int fb = blockIdx.y * 12 + blockIdx.x;      // 0..143
        for (int idx = fb * 256 + tid; idx < n4x + n4p; idx += 144 * 256) {
            const float* src; ushort* dst; int j;
            if (idx < n4x) { src = x; dst = xb; j = idx; }
            else { src = rpe + (size_t)POS_OFF * DIM; dst = rpeb; j = idx - n4x; }
            float4 f = ((const float4*)src)[j];
            ushort o[4] = {f2bf(f.x), f2bf(f.y), f2bf(f.z), f2bf(f.w)};
            *(uint2*)&dst[(size_t)j * 4] = *(uint2*)o;
        }
    }
}

// ---------- combined projections: QKV (blocks 0..431) + pos (432..503) ----
__global__ __launch_bounds__(256) void proj_all(
    const ushort* __restrict__ xb, const ushort* __restrict__ rpeb,
    const ushort* __restrict__ wsT,
    const float* __restrict__ bq, const float* __restrict__ qbias,
    const float* __restrict__ bk, const float* __restrict__ bv,
    const float* __restrict__ vbias,
    ushort* __restrict__ qk, ushort* __restrict__ vT, ushort* __restrict__ posKQ)
{
    __shared__ ushort As[128 * 64];
    __shared__ ushort Bs[128 * 64];
    const int tid = threadIdx.x;
    const int lane = tid & 63, w = tid >> 6;
    const int id = blockIdx.x;
    const bool qkvP = id < 432;
    const ushort* A; const ushort* Bt; int m0, n0, M;
    if (qkvP) {
        m0 = (id % 24) * 128; n0 = (id / 24) * 128;
        A = xb; Bt = wsT; M = NTOK;
    } else {
        int p = id - 432;
        m0 = (p % 6) * 128; n0 = (p / 6) * 128;
        A = rpeb; Bt = wsT + (size_t)3 * DIM * DIM; M = NPOS;
    }
    const int lr = lane >> 3;
    const int lc = (lane & 7) ^ (lr & 7);
    const ushort* ga[4]; const ushort* gb[4];
#pragma unroll
    for (int p = 0; p < 4; ++p) {
        int row = (w * 4 + p) * 8 + lr;
        int arow = m0 + row; if (arow > M - 1) arow = M - 1;
        ga[p] = A + (size_t)arow * DIM + lc * 8;
        gb[p] = Bt + (size_t)(n0 + row) * DIM + lc * 8;
    }
    floatx4 acc[4][4] = {};
    const int qr = (w >> 1) * 64, qc = (w & 1) * 64;
    const int lm = lane & 15, lk = lane >> 4;
    for (int k0 = 0; k0 < DIM; k0 += 64) {
#pragma unroll
        for (int p = 0; p < 4; ++p) {
            gld16(ga[p], As + (w * 4 + p) * 512);
            gld16(gb[p], Bs + (w * 4 + p) * 512);
            ga[p] += 64; gb[p] += 64;
        }
        __syncthreads();
#pragma unroll
        for (int kk = 0; kk < 2; ++kk) {
            int ch = (kk * 4 + lk) ^ (lm & 7);
            short8 af[4], bf[4];
#pragma unroll
            for (int t = 0; t < 4; ++t) {
                af[t] = *(const short8*)&As[(qr + t * 16 + lm) * 64 + ch * 8];
                bf[t] = *(const short8*)&Bs[(qc + t * 16 + lm) * 64 + ch * 8];
            }
#pragma unroll
            for (int i = 0; i < 4; ++i)
#pragma unroll
                for (int j = 0; j < 4; ++j)
                    acc[i][j] = MFMA(af[i], bf[j], acc[i][j], 0, 0, 0);
        }
        __syncthreads();
    }
    if (qkvP) {
#pragma unroll
        for (int i = 0; i < 4; ++i) {
            int mbase = m0 + qr + i * 16 + (lane >> 4) * 4;
            int bb = mbase / SEQ;
            int s0 = mbase - bb * SEQ;
#pragma unroll
            for (int j = 0; j < 4; ++j) {
                int n = n0 + qc + j * 16 + lm;
                float bs;
                if (n < 768) bs = bq[n] + qbias[n];
                else if (n < QKN) bs = bk[n - 768];
                else bs = bv[n - QKN] + vbias[n - QKN];
                if (n < QKN) {
#pragma unroll
                    for (int r = 0; r < 4; ++r)
                        qk[(size_t)(mbase + r) * QKN + n] = f2bf(acc[i][j][r] + bs);
                } else {
                    int c = n - QKN, h = c >> 6, d = c & 63;
                    ushort tmp[4];
#pragma unroll
                    for (int r = 0; r < 4; ++r) tmp[r] = f2bf(acc[i][j][r] + bs);
                    *(uint2*)&vT[(((size_t)bb * NH + h) * DH + d) * SEQ + s0] = *(uint2*)tmp;
                }
            }
        }
    } else {
#pragma unroll
        for (int i = 0; i < 4; ++i) {
            int mbase = m0 + qr + i * 16 + (lane >> 4) * 4;
#pragma unroll
            for (int j = 0; j < 4; ++j) {
                int n = n0 + qc + j * 16 + lm;
#pragma unroll
                for (int r = 0; r < 4; ++r) {
                    int row = mbase + r;
                    if (row < NPOS)
                        posKQ[(size_t)row * PN + n] = f2bf(acc[i][j][r]);
                }
            }
        }
    }
}

// ---------- 128x64-tile MFMA GEMM (output projection, 288 blocks) ---------
__global__ __launch_bounds__(256) void gemm128x64(
    const ushort* __restrict__ A, const ushort* __restrict__ Bt,
    const float* __restrict__ bias, float* __restrict__ outF,
    int M, int N, int K)
{
    __shared__ ushort As[128 * 64];
    __shared__ ushort Bs[64 * 64];
    const int tid = threadIdx.x;
    const int lane = tid & 63, w = tid >> 6;
    const int n0 = blockIdx.x * 64, m0 = blockIdx.y * 128;
    const int lr = lane >> 3;
    const int lc = (lane & 7) ^ (lr & 7);
    const ushort* ga[4]; const ushort* gb[2];
#pragma unroll
    for (int p = 0; p < 4; ++p) {
        int arow = m0 + (w * 4 + p) * 8 + lr; if (arow > M - 1) arow = M - 1;
        ga[p] = A + (size_t)arow * K + lc * 8;
    }
#pragma unroll
    for (int p = 0; p < 2; ++p)
        gb[p] = Bt + (size_t)(n0 + (w * 2 + p) * 8 + lr) * K + lc * 8;
    floatx4 acc[4][2] = {};
    const int qr = (w >> 1) * 64, qc = (w & 1) * 32;
    const int lm = lane & 15, lk = lane >> 4;
    for (int k0 = 0; k0 < K; k0 += 64) {
#pragma unroll
        for (int p = 0; p < 4; ++p) { gld16(ga[p], As + (w * 4 + p) * 512); ga[p] += 64; }
#pragma unroll
        for (int p = 0; p < 2; ++p) { gld16(gb[p], Bs + (w * 2 + p) * 512); gb[p] += 64; }
        __syncthreads();
#pragma unroll
        for (int kk = 0; kk < 2; ++kk) {
            int ch = (kk * 4 + lk) ^ (lm & 7);
            short8 af[4], bf[2];
#pragma unroll
            for (int t = 0; t < 4; ++t)
                af[t] = *(const short8*)&As[(qr + t * 16 + lm) * 64 + ch * 8];
#pragma unroll
            for (int t = 0; t < 2; ++t)
                bf[t] = *(const short8*)&Bs[(qc + t * 16 + lm) * 64 + ch * 8];
#pragma unroll
            for (int i = 0; i < 4; ++i)
#pragma unroll
                for (int j = 0; j < 2; ++j)
                    acc[i][j] = MFMA(af[i], bf[j], acc[i][j], 0, 0, 0);
        }
        __syncthreads();
    }
#pragma unroll
    for (int i = 0; i < 4; ++i) {
        int mbase = m0 + qr + i * 16 + (lane >> 4) * 4;
#pragma unroll
        for (int j = 0; j < 2; ++j) {
            int n = n0 + qc + j * 16 + lm;
            float bs = bias[n];
#pragma unroll
            for (int r = 0; r < 4; ++r) {
                int row = mbase + r;
                if (row < M) outF[(size_t)row * N + n] = acc[i][j][r] + bs;
            }
        }
    }
}

// ---------- fused attention v5: register-direct frags, 2 barriers/iter ----
// grid (6, 12, 8), 512 threads (8 waves). LDS only holds score exchange.
// s[i,j] = (q_i.k_j + q_i.Kp[t] + Qp[t].k_j)*0.125, t = j-i+383.
__global__ __launch_bounds__(512, 4) void attn_fused5(
    const ushort* __restrict__ qk, const ushort* __restrict__ vT,
    const ushort* __restrict__ posKQ, ushort* __restrict__ aob)
{
    __shared__ ushort ccpt[2][64 * 72];   // c2c scores / P (aliased), double-buffered
    __shared__ ushort dqs[64 * 72];       // dq pre-shifted: dqs[i][j] = dq[i][j-i+63]
    __shared__ ushort dks[64 * 72];       // dk pre-shifted: dks[i][j] = dk[j-i+63][j]
    __shared__ float rowsum[64];

    const int tid = threadIdx.x;
    const int lane = tid & 63, w = tid >> 6;
    const int i0 = blockIdx.x * 64;
    const int h = blockIdx.y, b = blockIdx.z;
    const int lm = lane & 15, lq = lane >> 4;
    const int trq = w >> 1;              // i row-tile (c2c/dq/PV)
    const int half = w & 1;
    const int exr = tid >> 3, exseg = tid & 7;

    if (tid < 64) rowsum[tid] = 0.f;

    // q fragments: register-resident for the whole kernel
    short8 qf[2];
    {
        const ushort* qr = qk + (size_t)(b * SEQ + i0 + trq * 16 + lm) * QKN + h * DH;
        qf[0] = *(const short8*)(qr + lq * 8);
        qf[1] = *(const short8*)(qr + 32 + lq * 8);
    }
    floatx4 occ[2] = {};

    for (int jt = 0; jt < 6; ++jt) {
        const int j0 = jt * 64;
        const int t0 = j0 - i0 + 320;    // t=127 row may overread into wsT pad
        ushort* cc = ccpt[jt & 1];

        // register loads (k rows, Qp band row) — issued up front
        short8 kd[4][2], qp[2];
#pragma unroll
        for (int s = 0; s < 4; ++s) {
            const ushort* kr = qk + (size_t)(b * SEQ + j0 + s * 16 + lm) * QKN + 768 + h * DH;
            kd[s][0] = *(const short8*)(kr + lq * 8);
            kd[s][1] = *(const short8*)(kr + 32 + lq * 8);
        }
        {
            const ushort* qpr = posKQ + (size_t)(t0 + w * 16 + lm) * PN + 768 + h * DH;
            qp[0] = *(const short8*)(qpr + lq * 8);
            qp[1] = *(const short8*)(qpr + 32 + lq * 8);
        }

        // dk: Qp-band @ k^T  (C rows = t, cols = j) -> diagonal pre-shift store
        {
            floatx4 e[4] = {};
#pragma unroll
            for (int kk = 0; kk < 2; ++kk)
#pragma unroll
                for (int s = 0; s < 4; ++s)
                    e[s] = MFMA(qp[kk], kd[s][kk], e[s], 0, 0, 0);
#pragma unroll
            for (int s = 0; s < 4; ++s) {
                int j = s * 16 + lm;
#pragma unroll
                for (int r = 0; r < 4; ++r) {
                    int t = w * 16 + lq * 4 + r;
                    int i = j - t + 63;
                    if ((unsigned)i < 64u) dks[i * 72 + j] = f2bf(e[s][r]);
                }
            }
        }
        // c2c: q @ k^T (reuses 2 of the kd fragments)
        {
            floatx4 a[2] = {};
#pragma unroll
            for (int kk = 0; kk < 2; ++kk)
#pragma unroll
                for (int s = 0; s < 2; ++s)
                    a[s] = MFMA(qf[kk], kd[half * 2 + s][kk], a[s], 0, 0, 0);
#pragma unroll
            for (int s = 0; s < 2; ++s) {
                int j = (half * 2 + s) * 16 + lm;
#pragma unroll
                for (int r = 0; r < 4; ++r)
                    cc[(trq * 16 + lq * 4 + r) * 72 + j] = f2bf(a[s][r]);
            }
        }
        // dq: q @ Kp-band^T (C rows = i, cols = t) -> diagonal pre-shift store
        {
            short8 kp[4][2];
#pragma unroll
            for (int s = 0; s < 4; ++s) {
                const ushort* kpr = posKQ + (size_t)(t0 + (half * 4 + s) * 16 + lm) * PN + h * DH;
                kp[s][0] = *(const short8*)(kpr + lq * 8);
                kp[s][1] = *(const short8*)(kpr + 32 + lq * 8);
            }
            floatx4 d[4] = {};
#pragma unroll
            for (int kk = 0; kk < 2; ++kk)
#pragma unroll
                for (int s = 0; s < 4; ++s)
                    d[s] = MFMA(qf[kk], kp[s][kk], d[s], 0, 0, 0);
#pragma unroll
            for (int s = 0; s < 4; ++s) {
                int t = (half * 4 + s) * 16 + lm;
#pragma unroll
                for (int r = 0; r < 4; ++r) {
                    int i = trq * 16 + lq * 4 + r;
                    int j = t + i - 63;
                    if ((unsigned)j < 64u) dqs[i * 72 + j] = f2bf(d[s][r]);
                }
            }
        }
        __syncthreads();                                   // (1) scores complete

        // V fragments for PV (loads fly during phase C)
        short8 vf[2][2];
#pragma unroll
        for (int s = 0; s < 2; ++s) {
            const ushort* vr = vT + ((size_t)(b * NH + h) * DH + (half * 2 + s) * 16 + lm) * SEQ + j0;
            vf[s][0] = *(const short8*)(vr + lq * 8);
            vf[s][1] = *(const short8*)(vr + 32 + lq * 8);
        }

        // phase C: gather three terms (contiguous b128), exp, rowsum, P->pt
        {
            uint4 c4 = *(const uint4*)&cc[exr * 72 + exseg * 8];
            uint4 q4 = *(const uint4*)&dqs[exr * 72 + exseg * 8];
            uint4 k4 = *(const uint4*)&dks[exr * 72 + exseg * 8];
            const ushort* cu = (const ushort*)&c4;
            const ushort* qu = (const ushort*)&q4;
            const ushort* ku = (const ushort*)&k4;
            float p[8]; float psum = 0.f;
#pragma unroll
            for (int c = 0; c < 8; ++c) {
                float sv = (bf2f(cu[c]) + bf2f(qu[c]) + bf2f(ku[c])) * 0.125f;
                p[c] = __expf(sv);
                psum += p[c];
            }
            psum += __shfl_xor(psum, 1);
            psum += __shfl_xor(psum, 2);
            psum += __shfl_xor(psum, 4);
            if (exseg == 0) rowsum[exr] += psum;
            ushort tmp[8];
#pragma unroll
            for (int c = 0; c < 8; ++c) tmp[c] = f2bf(p[c]);
            *(uint4*)&cc[exr * 72 + exseg * 8] = *(uint4*)tmp;   // pt (own cells)
        }
        __syncthreads();                                   // (2) pt visible

        // phase D: PV accumulate (overlaps next iter's loads/score phase)
#pragma unroll
        for (int kk = 0; kk < 2; ++kk) {
            short8 af = *(const short8*)&cc[(trq * 16 + lm) * 72 + kk * 32 + lq * 8];
#pragma unroll
            for (int s = 0; s < 2; ++s)
                occ[s] = MFMA(af, vf[s][kk], occ[s], 0, 0, 0);
        }
    }

#pragma unroll
    for (int s = 0; s < 2; ++s) {
#pragma unroll
        for (int r = 0; r < 4; ++r) {
            int row = trq * 16 + lq * 4 + r;
            float ov = occ[s][r] / rowsum[row];
            aob[(size_t)(b * SEQ + i0 + row) * DIM + h * DH + (half * 2 + s) * 16 + lm] = f2bf(ov);
        }
    }
}

extern "C" void kernel_launch(void* const* d_in, const int* in_sizes, int n_in,
                              void* d_out, int out_size, void* d_ws, size_t ws_size,
                              hipStream_t stream) {
    const float* x   = (const float*)d_in[0];
    const float* rpe = (const float*)d_in[1];
    const float* Wq  = (const float*)d_in[2];
    const float* bq  = (const float*)d_in[3];
    const float* Wk  = (const float*)d_in[4];
    const float* bk  = (const float*)d_in[5];
    const float* Wv  = (const float*)d_in[6];
    const float* bv  = (const float*)d_in[7];
    const float* qbias = (const float*)d_in[8];
    const float* vbias = (const float*)d_in[9];
    const float* Wpk = (const float*)d_in[10];
    const float* Wpq = (const float*)d_in[11];
    const float* Wo  = (const float*)d_in[12];
    const float* bo  = (const float*)d_in[13];
    float* out = (float*)d_out;

    char* ws = (char*)d_ws;
    ushort* xb    = (ushort*)ws; ws += (size_t)NTOK * DIM * 2;
    ushort* qkbuf = (ushort*)ws; ws += (size_t)NTOK * QKN * 2;
    ushort* vT    = (ushort*)ws; ws += (size_t)NTOK * DIM * 2;
    ushort* aob   = (ushort*)ws; ws += (size_t)NTOK * DIM * 2;
    ushort* rpeb  = (ushort*)ws; ws += (size_t)NPOS * DIM * 2;
    ushort* posKQ = (ushort*)ws; ws += (size_t)NPOS * PN * 2;
    ushort* wsT   = (ushort*)ws; ws += (size_t)6 * DIM * DIM * 2;   // must follow posKQ (t=767 overread pad)

    // 1) converts + weight transposes
    prep<<<dim3(12, 12, 7), dim3(256), 0, stream>>>(
        Wq, Wk, Wv, Wpk, Wpq, Wo, x, rpe, wsT, xb, rpeb);
    // 2) QKV projection + positional projections in one launch (504 blocks)
    proj_all<<<dim3(504), dim3(256), 0, stream>>>(
        xb, rpeb, wsT, bq, qbias, bk, bv, vbias, qkbuf, vT, posKQ);
    // 3) fused attention (register-direct fragments)
    attn_fused5<<<dim3(SEQ / 64, NH, BATCH), dim3(512), 0, stream>>>(qkbuf, vT, posKQ, aob);
    // 4) output projection -> fp32 d_out (288 blocks)
    gemm128x64<<<dim3(DIM / 64, NTOK / 128), dim3(256), 0, stream>>>(
        aob, wsT + (size_t)5 * DIM * DIM, bo, out, NTOK, DIM, DIM);
}

// Round 9
// 243.364 us; speedup vs baseline: 1.1170x; 1.1170x over previous
//
#include <hip/hip_runtime.h>
#include <hip/hip_bf16.h>
#include <math.h>

#define BATCH 8
#define SEQ 384
#define DIM 768
#define NH 12
#define DH 64
#define NPOS 767
#define POS_OFF 128
#define NTOK (BATCH * SEQ)
#define QKN 1536
#define QKVN 2304
#define PN 1536

typedef __attribute__((ext_vector_type(8))) short short8;
typedef __attribute__((ext_vector_type(4))) float floatx4;
typedef unsigned int u32;

__device__ __forceinline__ ushort f2bf(float f) {
    __hip_bfloat16 h = __float2bfloat16(f);
    return *reinterpret_cast<ushort*>(&h);
}
__device__ __forceinline__ float bf2f(ushort u) {
    u32 x = ((u32)u) << 16;
    float f; __builtin_memcpy(&f, &x, 4); return f;
}

// async global->LDS, 16B per lane; lds dest = wave-uniform base + lane*16
__device__ __forceinline__ void gld16(const ushort* g, ushort* l) {
    __builtin_amdgcn_global_load_lds(
        (const __attribute__((address_space(1))) u32*)g,
        (__attribute__((address_space(3))) u32*)l, 16, 0, 0);
}

#define MFMA __builtin_amdgcn_mfma_f32_16x16x32_bf16

// ---------- prep: weight transposes (z<6) + row converts (z==6) -----------
__global__ __launch_bounds__(256) void prep(
    const float* W0, const float* W1, const float* W2,
    const float* W3, const float* W4, const float* W5,
    const float* x, const float* rpe,
    ushort* __restrict__ wsT, ushort* __restrict__ xb, ushort* __restrict__ rpeb)
{
    const int tid = threadIdx.x;
    if (blockIdx.z < 6) {
        __shared__ float t[64][65];
        const float* srcs[6] = {W0, W1, W2, W3, W4, W5};
        const float* in = srcs[blockIdx.z];
        ushort* out = wsT + (size_t)blockIdx.z * DIM * DIM;
        const int r0 = blockIdx.y * 64, c0 = blockIdx.x * 64;
        for (int p = 0; p < 16; ++p) {
            int e = tid + p * 256, i = e >> 6, j = e & 63;
            t[i][j] = in[(size_t)(r0 + i) * DIM + c0 + j];
        }
        __syncthreads();
        for (int p = 0; p < 16; ++p) {
            int e = tid + p * 256, i = e >> 6, j = e & 63;
            out[(size_t)(c0 + i) * DIM + r0 + j] = f2bf(t[j][i]);
        }
    } else {
        const int n4x = NTOK * DIM / 4;
        const int n4p = NPOS * DIM / 4;
        const int fb = blockIdx.y * 12 + blockIdx.x;      // 0..143
        for (int idx = fb * 256 + tid; idx < n4x + n4p; idx += 144 * 256) {
            const float* src; ushort* dst; int j;
            if (idx < n4x) { src = x; dst = xb; j = idx; }
            else { src = rpe + (size_t)POS_OFF * DIM; dst = rpeb; j = idx - n4x; }
            float4 f = ((const float4*)src)[j];
            ushort o[4] = {f2bf(f.x), f2bf(f.y), f2bf(f.z), f2bf(f.w)};
            *(uint2*)&dst[(size_t)j * 4] = *(uint2*)o;
        }
    }
}

// ---------- combined projections: QKV (blocks 0..431) + pos (432..503) ----
__global__ __launch_bounds__(256) void proj_all(
    const ushort* __restrict__ xb, const ushort* __restrict__ rpeb,
    const ushort* __restrict__ wsT,
    const float* __restrict__ bq, const float* __restrict__ qbias,
    const float* __restrict__ bk, const float* __restrict__ bv,
    const float* __restrict__ vbias,
    ushort* __restrict__ qk, ushort* __restrict__ vT, ushort* __restrict__ posKQ)
{
    __shared__ ushort As[128 * 64];
    __shared__ ushort Bs[128 * 64];
    const int tid = threadIdx.x;
    const int lane = tid & 63, w = tid >> 6;
    const int id = blockIdx.x;
    const bool qkvP = id < 432;
    const ushort* A; const ushort* Bt; int m0, n0, M;
    if (qkvP) {
        m0 = (id % 24) * 128; n0 = (id / 24) * 128;
        A = xb; Bt = wsT; M = NTOK;
    } else {
        int p = id - 432;
        m0 = (p % 6) * 128; n0 = (p / 6) * 128;
        A = rpeb; Bt = wsT + (size_t)3 * DIM * DIM; M = NPOS;
    }
    const int lr = lane >> 3;
    const int lc = (lane & 7) ^ (lr & 7);
    const ushort* ga[4]; const ushort* gb[4];
#pragma unroll
    for (int p = 0; p < 4; ++p) {
        int row = (w * 4 + p) * 8 + lr;
        int arow = m0 + row; if (arow > M - 1) arow = M - 1;
        ga[p] = A + (size_t)arow * DIM + lc * 8;
        gb[p] = Bt + (size_t)(n0 + row) * DIM + lc * 8;
    }
    floatx4 acc[4][4] = {};
    const int qr = (w >> 1) * 64, qc = (w & 1) * 64;
    const int lm = lane & 15, lk = lane >> 4;
    for (int k0 = 0; k0 < DIM; k0 += 64) {
#pragma unroll
        for (int p = 0; p < 4; ++p) {
            gld16(ga[p], As + (w * 4 + p) * 512);
            gld16(gb[p], Bs + (w * 4 + p) * 512);
            ga[p] += 64; gb[p] += 64;
        }
        __syncthreads();
#pragma unroll
        for (int kk = 0; kk < 2; ++kk) {
            int ch = (kk * 4 + lk) ^ (lm & 7);
            short8 af[4], bf[4];
#pragma unroll
            for (int t = 0; t < 4; ++t) {
                af[t] = *(const short8*)&As[(qr + t * 16 + lm) * 64 + ch * 8];
                bf[t] = *(const short8*)&Bs[(qc + t * 16 + lm) * 64 + ch * 8];
            }
#pragma unroll
            for (int i = 0; i < 4; ++i)
#pragma unroll
                for (int j = 0; j < 4; ++j)
                    acc[i][j] = MFMA(af[i], bf[j], acc[i][j], 0, 0, 0);
        }
        __syncthreads();
    }
    if (qkvP) {
#pragma unroll
        for (int i = 0; i < 4; ++i) {
            int mbase = m0 + qr + i * 16 + (lane >> 4) * 4;
            int bb = mbase / SEQ;
            int s0 = mbase - bb * SEQ;
#pragma unroll
            for (int j = 0; j < 4; ++j) {
                int n = n0 + qc + j * 16 + lm;
                float bs;
                if (n < 768) bs = bq[n] + qbias[n];
                else if (n < QKN) bs = bk[n - 768];
                else bs = bv[n - QKN] + vbias[n - QKN];
                if (n < QKN) {
#pragma unroll
                    for (int r = 0; r < 4; ++r)
                        qk[(size_t)(mbase + r) * QKN + n] = f2bf(acc[i][j][r] + bs);
                } else {
                    int c = n - QKN, h = c >> 6, d = c & 63;
                    ushort tmp[4];
#pragma unroll
                    for (int r = 0; r < 4; ++r) tmp[r] = f2bf(acc[i][j][r] + bs);
                    *(uint2*)&vT[(((size_t)bb * NH + h) * DH + d) * SEQ + s0] = *(uint2*)tmp;
                }
            }
        }
    } else {
#pragma unroll
        for (int i = 0; i < 4; ++i) {
            int mbase = m0 + qr + i * 16 + (lane >> 4) * 4;
#pragma unroll
            for (int j = 0; j < 4; ++j) {
                int n = n0 + qc + j * 16 + lm;
#pragma unroll
                for (int r = 0; r < 4; ++r) {
                    int row = mbase + r;
                    if (row < NPOS)
                        posKQ[(size_t)row * PN + n] = f2bf(acc[i][j][r]);
                }
            }
        }
    }
}

// ---------- 128x64-tile MFMA GEMM (output projection, 288 blocks) ---------
__global__ __launch_bounds__(256) void gemm128x64(
    const ushort* __restrict__ A, const ushort* __restrict__ Bt,
    const float* __restrict__ bias, float* __restrict__ outF,
    int M, int N, int K)
{
    __shared__ ushort As[128 * 64];
    __shared__ ushort Bs[64 * 64];
    const int tid = threadIdx.x;
    const int lane = tid & 63, w = tid >> 6;
    const int n0 = blockIdx.x * 64, m0 = blockIdx.y * 128;
    const int lr = lane >> 3;
    const int lc = (lane & 7) ^ (lr & 7);
    const ushort* ga[4]; const ushort* gb[2];
#pragma unroll
    for (int p = 0; p < 4; ++p) {
        int arow = m0 + (w * 4 + p) * 8 + lr; if (arow > M - 1) arow = M - 1;
        ga[p] = A + (size_t)arow * K + lc * 8;
    }
#pragma unroll
    for (int p = 0; p < 2; ++p)
        gb[p] = Bt + (size_t)(n0 + (w * 2 + p) * 8 + lr) * K + lc * 8;
    floatx4 acc[4][2] = {};
    const int qr = (w >> 1) * 64, qc = (w & 1) * 32;
    const int lm = lane & 15, lk = lane >> 4;
    for (int k0 = 0; k0 < K; k0 += 64) {
#pragma unroll
        for (int p = 0; p < 4; ++p) { gld16(ga[p], As + (w * 4 + p) * 512); ga[p] += 64; }
#pragma unroll
        for (int p = 0; p < 2; ++p) { gld16(gb[p], Bs + (w * 2 + p) * 512); gb[p] += 64; }
        __syncthreads();
#pragma unroll
        for (int kk = 0; kk < 2; ++kk) {
            int ch = (kk * 4 + lk) ^ (lm & 7);
            short8 af[4], bf[2];
#pragma unroll
            for (int t = 0; t < 4; ++t)
                af[t] = *(const short8*)&As[(qr + t * 16 + lm) * 64 + ch * 8];
#pragma unroll
            for (int t = 0; t < 2; ++t)
                bf[t] = *(const short8*)&Bs[(qc + t * 16 + lm) * 64 + ch * 8];
#pragma unroll
            for (int i = 0; i < 4; ++i)
#pragma unroll
                for (int j = 0; j < 2; ++j)
                    acc[i][j] = MFMA(af[i], bf[j], acc[i][j], 0, 0, 0);
        }
        __syncthreads();
    }
#pragma unroll
    for (int i = 0; i < 4; ++i) {
        int mbase = m0 + qr + i * 16 + (lane >> 4) * 4;
#pragma unroll
        for (int j = 0; j < 2; ++j) {
            int n = n0 + qc + j * 16 + lm;
            float bs = bias[n];
#pragma unroll
            for (int r = 0; r < 4; ++r) {
                int row = mbase + r;
                if (row < M) outF[(size_t)row * N + n] = acc[i][j][r] + bs;
            }
        }
    }
}

// ---------- fused attention v6: register-direct, 256 thr, no spill --------
// grid (6, 12, 8), 256 threads (4 waves). Wave w owns i-tile w.
// s[i,j] = (q_i.k_j + q_i.Kp[t] + Qp[t].k_j)*0.125, t = j-i+383.
// VGPR budget: kd 32 + qp/kp 8 + acc 16 + qf 8 + occ 16 + addr ~25 ≈ 105 < 128.
__global__ __launch_bounds__(256, 4) void attn_fused6(
    const ushort* __restrict__ qk, const ushort* __restrict__ vT,
    const ushort* __restrict__ posKQ, ushort* __restrict__ aob)
{
    __shared__ ushort ccpt[2][64 * 72];   // c2c scores / P (aliased), double-buffered
    __shared__ ushort dqs[64 * 72];       // dq pre-shifted: dqs[i][j] = dq[i][j-i+63]
    __shared__ ushort dks[64 * 72];       // dk pre-shifted: dks[i][j] = dk[j-i+63][j]
    __shared__ float rowsum[64];

    const int tid = threadIdx.x;
    const int lane = tid & 63, w = tid >> 6;     // 4 waves; wave w = i-tile w
    const int i0 = blockIdx.x * 64;
    const int h = blockIdx.y, b = blockIdx.z;
    const int lm = lane & 15, lq = lane >> 4;
    const int exr = tid >> 2, exseg = tid & 3;   // 64 rows x 4 col-segments

    if (tid < 64) rowsum[tid] = 0.f;

    // q fragments: register-resident for the whole kernel
    short8 qf[2];
    {
        const ushort* qr = qk + (size_t)(b * SEQ + i0 + w * 16 + lm) * QKN + h * DH;
        qf[0] = *(const short8*)(qr + lq * 8);
        qf[1] = *(const short8*)(qr + 32 + lq * 8);
    }
    floatx4 occ[4] = {};

    for (int jt = 0; jt < 6; ++jt) {
        const int j0 = jt * 64;
        const int t0 = j0 - i0 + 320;    // t=127 row may overread into wsT pad (discarded)
        ushort* cc = ccpt[jt & 1];

        // k fragments for all 4 j-tiles (reused by dk and c2c)
        short8 kd[4][2];
#pragma unroll
        for (int s = 0; s < 4; ++s) {
            const ushort* kr = qk + (size_t)(b * SEQ + j0 + s * 16 + lm) * QKN + 768 + h * DH;
            kd[s][0] = *(const short8*)(kr + lq * 8);
            kd[s][1] = *(const short8*)(kr + 32 + lq * 8);
        }
        // dk: Qp-band @ k^T; wave w covers t-tiles {2w, 2w+1} x 4 j-tiles
#pragma unroll
        for (int tt = 0; tt < 2; ++tt) {
            int ttile = w * 2 + tt;
            short8 qp[2];
            const ushort* qpr = posKQ + (size_t)(t0 + ttile * 16 + lm) * PN + 768 + h * DH;
            qp[0] = *(const short8*)(qpr + lq * 8);
            qp[1] = *(const short8*)(qpr + 32 + lq * 8);
            floatx4 e[4] = {};
#pragma unroll
            for (int s = 0; s < 4; ++s) {
                e[s] = MFMA(qp[0], kd[s][0], e[s], 0, 0, 0);
                e[s] = MFMA(qp[1], kd[s][1], e[s], 0, 0, 0);
            }
#pragma unroll
            for (int s = 0; s < 4; ++s) {
                int j = s * 16 + lm;
#pragma unroll
                for (int r = 0; r < 4; ++r) {
                    int t = ttile * 16 + lq * 4 + r;
                    int i = j - t + 63;
                    if ((unsigned)i < 64u) dks[i * 72 + j] = f2bf(e[s][r]);
                }
            }
        }
        // c2c: q @ k^T (reuses kd); i-tile w x 4 j-tiles
        {
            floatx4 a[4] = {};
#pragma unroll
            for (int s = 0; s < 4; ++s) {
                a[s] = MFMA(qf[0], kd[s][0], a[s], 0, 0, 0);
                a[s] = MFMA(qf[1], kd[s][1], a[s], 0, 0, 0);
            }
#pragma unroll
            for (int s = 0; s < 4; ++s) {
                int j = s * 16 + lm;
#pragma unroll
                for (int r = 0; r < 4; ++r)
                    cc[(w * 16 + lq * 4 + r) * 72 + j] = f2bf(a[s][r]);
            }
        }
        // dq: q @ Kp-band^T; i-tile w x 8 t-tiles, kp streamed
#pragma unroll
        for (int s8 = 0; s8 < 8; ++s8) {
            short8 kp[2];
            const ushort* kpr = posKQ + (size_t)(t0 + s8 * 16 + lm) * PN + h * DH;
            kp[0] = *(const short8*)(kpr + lq * 8);
            kp[1] = *(const short8*)(kpr + 32 + lq * 8);
            floatx4 d = {};
            d = MFMA(qf[0], kp[0], d, 0, 0, 0);
            d = MFMA(qf[1], kp[1], d, 0, 0, 0);
            int t = s8 * 16 + lm;
#pragma unroll
            for (int r = 0; r < 4; ++r) {
                int i = w * 16 + lq * 4 + r;
                int j = t + i - 63;
                if ((unsigned)j < 64u) dqs[i * 72 + j] = f2bf(d[r]);
            }
        }
        __syncthreads();                                   // (1) scores complete

        // phase C: gather 3 terms (b128), exp, rowsum, P in-place
        {
            float psum = 0.f;
            ushort pv[16];
#pragma unroll
            for (int hh = 0; hh < 2; ++hh) {
                int off = exr * 72 + exseg * 16 + hh * 8;
                uint4 c4 = *(const uint4*)&cc[off];
                uint4 q4 = *(const uint4*)&dqs[off];
                uint4 k4 = *(const uint4*)&dks[off];
                const ushort* cu = (const ushort*)&c4;
                const ushort* qu = (const ushort*)&q4;
                const ushort* ku = (const ushort*)&k4;
#pragma unroll
                for (int c = 0; c < 8; ++c) {
                    float sv = (bf2f(cu[c]) + bf2f(qu[c]) + bf2f(ku[c])) * 0.125f;
                    float pe = __expf(sv);
                    psum += pe;
                    pv[hh * 8 + c] = f2bf(pe);
                }
            }
            psum += __shfl_xor(psum, 1);
            psum += __shfl_xor(psum, 2);
            if (exseg == 0) rowsum[exr] += psum;
#pragma unroll
            for (int hh = 0; hh < 2; ++hh)
                *(uint4*)&cc[exr * 72 + exseg * 16 + hh * 8] = *(uint4*)&pv[hh * 8];
        }
        __syncthreads();                                   // (2) pt visible

        // PV: i-tile w x 4 d-tiles, vf streamed; overlaps next iter safely
        // (next iter writes the OTHER cc buffer; dqs/dks not read here)
#pragma unroll
        for (int dt = 0; dt < 4; ++dt) {
            short8 vf[2];
            const ushort* vr = vT + ((size_t)(b * NH + h) * DH + dt * 16 + lm) * SEQ + j0;
            vf[0] = *(const short8*)(vr + lq * 8);
            vf[1] = *(const short8*)(vr + 32 + lq * 8);
#pragma unroll
            for (int kk = 0; kk < 2; ++kk) {
                short8 af = *(const short8*)&cc[(w * 16 + lm) * 72 + kk * 32 + lq * 8];
                occ[dt] = MFMA(af, vf[kk], occ[dt], 0, 0, 0);
            }
        }
    }

#pragma unroll
    for (int dt = 0; dt < 4; ++dt) {
#pragma unroll
        for (int r = 0; r < 4; ++r) {
            int row = w * 16 + lq * 4 + r;
            float ov = occ[dt][r] / rowsum[row];
            aob[(size_t)(b * SEQ + i0 + row) * DIM + h * DH + dt * 16 + lm] = f2bf(ov);
        }
    }
}

extern "C" void kernel_launch(void* const* d_in, const int* in_sizes, int n_in,
                              void* d_out, int out_size, void* d_ws, size_t ws_size,
                              hipStream_t stream) {
    const float* x   = (const float*)d_in[0];
    const float* rpe = (const float*)d_in[1];
    const float* Wq  = (const float*)d_in[2];
    const float* bq  = (const float*)d_in[3];
    const float* Wk  = (const float*)d_in[4];
    const float* bk  = (const float*)d_in[5];
    const float* Wv  = (const float*)d_in[6];
    const float* bv  = (const float*)d_in[7];
    const float* qbias = (const float*)d_in[8];
    const float* vbias = (const float*)d_in[9];
    const float* Wpk = (const float*)d_in[10];
    const float* Wpq = (const float*)d_in[11];
    const float* Wo  = (const float*)d_in[12];
    const float* bo  = (const float*)d_in[13];
    float* out = (float*)d_out;

    char* ws = (char*)d_ws;
    ushort* xb    = (ushort*)ws; ws += (size_t)NTOK * DIM * 2;
    ushort* qkbuf = (ushort*)ws; ws += (size_t)NTOK * QKN * 2;
    ushort* vT    = (ushort*)ws; ws += (size_t)NTOK * DIM * 2;
    ushort* aob   = (ushort*)ws; ws += (size_t)NTOK * DIM * 2;
    ushort* rpeb  = (ushort*)ws; ws += (size_t)NPOS * DIM * 2;
    ushort* posKQ = (ushort*)ws; ws += (size_t)NPOS * PN * 2;
    ushort* wsT   = (ushort*)ws; ws += (size_t)6 * DIM * DIM * 2;   // must follow posKQ (t=767 overread pad)

    // 1) converts + weight transposes
    prep<<<dim3(12, 12, 7), dim3(256), 0, stream>>>(
        Wq, Wk, Wv, Wpk, Wpq, Wo, x, rpe, wsT, xb, rpeb);
    // 2) QKV projection + positional projections in one launch (504 blocks)
    proj_all<<<dim3(504), dim3(256), 0, stream>>>(
        xb, rpeb, wsT, bq, qbias, bk, bv, vbias, qkbuf, vT, posKQ);
    // 3) fused attention (register-direct fragments, 256 threads, no spill)
    attn_fused6<<<dim3(SEQ / 64, NH, BATCH), dim3(256), 0, stream>>>(qkbuf, vT, posKQ, aob);
    // 4) output projection -> fp32 d_out (288 blocks)
    gemm128x64<<<dim3(DIM / 64, NTOK / 128), dim3(256), 0, stream>>>(
        aob, wsT + (size_t)5 * DIM * DIM, bo, out, NTOK, DIM, DIM);
}

// Round 10
// 211.410 us; speedup vs baseline: 1.2858x; 1.1511x over previous
//
#include <hip/hip_runtime.h>
#include <hip/hip_bf16.h>
#include <math.h>

#define BATCH 8
#define SEQ 384
#define DIM 768
#define NH 12
#define DH 64
#define NPOS 767
#define POS_OFF 128
#define NTOK (BATCH * SEQ)
#define QKN 1536
#define QKVN 2304
#define PN 1536

typedef __attribute__((ext_vector_type(8))) short short8;
typedef __attribute__((ext_vector_type(4))) float floatx4;
typedef unsigned int u32;

__device__ __forceinline__ ushort f2bf(float f) {
    __hip_bfloat16 h = __float2bfloat16(f);
    return *reinterpret_cast<ushort*>(&h);
}
__device__ __forceinline__ float bf2f(ushort u) {
    u32 x = ((u32)u) << 16;
    float f; __builtin_memcpy(&f, &x, 4); return f;
}

// async global->LDS, 16B per lane; lds dest = wave-uniform base + lane*16
__device__ __forceinline__ void gld16(const ushort* g, ushort* l) {
    __builtin_amdgcn_global_load_lds(
        (const __attribute__((address_space(1))) u32*)g,
        (__attribute__((address_space(3))) u32*)l, 16, 0, 0);
}

#define MFMA __builtin_amdgcn_mfma_f32_16x16x32_bf16

// ---------- prep: weight transposes (z<6) + row converts (z==6) -----------
__global__ __launch_bounds__(256) void prep(
    const float* W0, const float* W1, const float* W2,
    const float* W3, const float* W4, const float* W5,
    const float* x, const float* rpe,
    ushort* __restrict__ wsT, ushort* __restrict__ xb, ushort* __restrict__ rpeb)
{
    const int tid = threadIdx.x;
    if (blockIdx.z < 6) {
        __shared__ float t[64][65];
        const float* srcs[6] = {W0, W1, W2, W3, W4, W5};
        const float* in = srcs[blockIdx.z];
        ushort* out = wsT + (size_t)blockIdx.z * DIM * DIM;
        const int r0 = blockIdx.y * 64, c0 = blockIdx.x * 64;
        for (int p = 0; p < 16; ++p) {
            int e = tid + p * 256, i = e >> 6, j = e & 63;
            t[i][j] = in[(size_t)(r0 + i) * DIM + c0 + j];
        }
        __syncthreads();
        for (int p = 0; p < 16; ++p) {
            int e = tid + p * 256, i = e >> 6, j = e & 63;
            out[(size_t)(c0 + i) * DIM + r0 + j] = f2bf(t[j][i]);
        }
    } else {
        const int n4x = NTOK * DIM / 4;
        const int n4p = NPOS * DIM / 4;
        const int fb = blockIdx.y * 12 + blockIdx.x;      // 0..143
        for (int idx = fb * 256 + tid; idx < n4x + n4p; idx += 144 * 256) {
            const float* src; ushort* dst; int j;
            if (idx < n4x) { src = x; dst = xb; j = idx; }
            else { src = rpe + (size_t)POS_OFF * DIM; dst = rpeb; j = idx - n4x; }
            float4 f = ((const float4*)src)[j];
            ushort o[4] = {f2bf(f.x), f2bf(f.y), f2bf(f.z), f2bf(f.w)};
            *(uint2*)&dst[(size_t)j * 4] = *(uint2*)o;
        }
    }
}

// ---------- combined projections: QKV (blocks 0..431) + pos (432..503) ----
__global__ __launch_bounds__(256) void proj_all(
    const ushort* __restrict__ xb, const ushort* __restrict__ rpeb,
    const ushort* __restrict__ wsT,
    const float* __restrict__ bq, const float* __restrict__ qbias,
    const float* __restrict__ bk, const float* __restrict__ bv,
    const float* __restrict__ vbias,
    ushort* __restrict__ qk, ushort* __restrict__ vT, ushort* __restrict__ posKQ)
{
    __shared__ ushort As[128 * 64];
    __shared__ ushort Bs[128 * 64];
    const int tid = threadIdx.x;
    const int lane = tid & 63, w = tid >> 6;
    const int id = blockIdx.x;
    const bool qkvP = id < 432;
    const ushort* A; const ushort* Bt; int m0, n0, M;
    if (qkvP) {
        m0 = (id % 24) * 128; n0 = (id / 24) * 128;
        A = xb; Bt = wsT; M = NTOK;
    } else {
        int p = id - 432;
        m0 = (p % 6) * 128; n0 = (p / 6) * 128;
        A = rpeb; Bt = wsT + (size_t)3 * DIM * DIM; M = NPOS;
    }
    const int lr = lane >> 3;
    const int lc = (lane & 7) ^ (lr & 7);
    const ushort* ga[4]; const ushort* gb[4];
#pragma unroll
    for (int p = 0; p < 4; ++p) {
        int row = (w * 4 + p) * 8 + lr;
        int arow = m0 + row; if (arow > M - 1) arow = M - 1;
        ga[p] = A + (size_t)arow * DIM + lc * 8;
        gb[p] = Bt + (size_t)(n0 + row) * DIM + lc * 8;
    }
    floatx4 acc[4][4] = {};
    const int qr = (w >> 1) * 64, qc = (w & 1) * 64;
    const int lm = lane & 15, lk = lane >> 4;
    for (int k0 = 0; k0 < DIM; k0 += 64) {
#pragma unroll
        for (int p = 0; p < 4; ++p) {
            gld16(ga[p], As + (w * 4 + p) * 512);
            gld16(gb[p], Bs + (w * 4 + p) * 512);
            ga[p] += 64; gb[p] += 64;
        }
        __syncthreads();
#pragma unroll
        for (int kk = 0; kk < 2; ++kk) {
            int ch = (kk * 4 + lk) ^ (lm & 7);
            short8 af[4], bf[4];
#pragma unroll
            for (int t = 0; t < 4; ++t) {
                af[t] = *(const short8*)&As[(qr + t * 16 + lm) * 64 + ch * 8];
                bf[t] = *(const short8*)&Bs[(qc + t * 16 + lm) * 64 + ch * 8];
            }
#pragma unroll
            for (int i = 0; i < 4; ++i)
#pragma unroll
                for (int j = 0; j < 4; ++j)
                    acc[i][j] = MFMA(af[i], bf[j], acc[i][j], 0, 0, 0);
        }
        __syncthreads();
    }
    if (qkvP) {
#pragma unroll
        for (int i = 0; i < 4; ++i) {
            int mbase = m0 + qr + i * 16 + (lane >> 4) * 4;
            int bb = mbase / SEQ;
            int s0 = mbase - bb * SEQ;
#pragma unroll
            for (int j = 0; j < 4; ++j) {
                int n = n0 + qc + j * 16 + lm;
                float bs;
                if (n < 768) bs = bq[n] + qbias[n];
                else if (n < QKN) bs = bk[n - 768];
                else bs = bv[n - QKN] + vbias[n - QKN];
                if (n < QKN) {
#pragma unroll
                    for (int r = 0; r < 4; ++r)
                        qk[(size_t)(mbase + r) * QKN + n] = f2bf(acc[i][j][r] + bs);
                } else {
                    int c = n - QKN, h = c >> 6, d = c & 63;
                    ushort tmp[4];
#pragma unroll
                    for (int r = 0; r < 4; ++r) tmp[r] = f2bf(acc[i][j][r] + bs);
                    *(uint2*)&vT[(((size_t)bb * NH + h) * DH + d) * SEQ + s0] = *(uint2*)tmp;
                }
            }
        }
    } else {
#pragma unroll
        for (int i = 0; i < 4; ++i) {
            int mbase = m0 + qr + i * 16 + (lane >> 4) * 4;
#pragma unroll
            for (int j = 0; j < 4; ++j) {
                int n = n0 + qc + j * 16 + lm;
#pragma unroll
                for (int r = 0; r < 4; ++r) {
                    int row = mbase + r;
                    if (row < NPOS)
                        posKQ[(size_t)row * PN + n] = f2bf(acc[i][j][r]);
                }
            }
        }
    }
}

// ---------- 128x64-tile MFMA GEMM (output projection, 288 blocks) ---------
__global__ __launch_bounds__(256) void gemm128x64(
    const ushort* __restrict__ A, const ushort* __restrict__ Bt,
    const float* __restrict__ bias, float* __restrict__ outF,
    int M, int N, int K)
{
    __shared__ ushort As[128 * 64];
    __shared__ ushort Bs[64 * 64];
    const int tid = threadIdx.x;
    const int lane = tid & 63, w = tid >> 6;
    const int n0 = blockIdx.x * 64, m0 = blockIdx.y * 128;
    const int lr = lane >> 3;
    const int lc = (lane & 7) ^ (lr & 7);
    const ushort* ga[4]; const ushort* gb[2];
#pragma unroll
    for (int p = 0; p < 4; ++p) {
        int arow = m0 + (w * 4 + p) * 8 + lr; if (arow > M - 1) arow = M - 1;
        ga[p] = A + (size_t)arow * K + lc * 8;
    }
#pragma unroll
    for (int p = 0; p < 2; ++p)
        gb[p] = Bt + (size_t)(n0 + (w * 2 + p) * 8 + lr) * K + lc * 8;
    floatx4 acc[4][2] = {};
    const int qr = (w >> 1) * 64, qc = (w & 1) * 32;
    const int lm = lane & 15, lk = lane >> 4;
    for (int k0 = 0; k0 < K; k0 += 64) {
#pragma unroll
        for (int p = 0; p < 4; ++p) { gld16(ga[p], As + (w * 4 + p) * 512); ga[p] += 64; }
#pragma unroll
        for (int p = 0; p < 2; ++p) { gld16(gb[p], Bs + (w * 2 + p) * 512); gb[p] += 64; }
        __syncthreads();
#pragma unroll
        for (int kk = 0; kk < 2; ++kk) {
            int ch = (kk * 4 + lk) ^ (lm & 7);
            short8 af[4], bf[2];
#pragma unroll
            for (int t = 0; t < 4; ++t)
                af[t] = *(const short8*)&As[(qr + t * 16 + lm) * 64 + ch * 8];
#pragma unroll
            for (int t = 0; t < 2; ++t)
                bf[t] = *(const short8*)&Bs[(qc + t * 16 + lm) * 64 + ch * 8];
#pragma unroll
            for (int i = 0; i < 4; ++i)
#pragma unroll
                for (int j = 0; j < 2; ++j)
                    acc[i][j] = MFMA(af[i], bf[j], acc[i][j], 0, 0, 0);
        }
        __syncthreads();
    }
#pragma unroll
    for (int i = 0; i < 4; ++i) {
        int mbase = m0 + qr + i * 16 + (lane >> 4) * 4;
#pragma unroll
        for (int j = 0; j < 2; ++j) {
            int n = n0 + qc + j * 16 + lm;
            float bs = bias[n];
#pragma unroll
            for (int r = 0; r < 4; ++r) {
                int row = mbase + r;
                if (row < M) outF[(size_t)row * N + n] = acc[i][j][r] + bs;
            }
        }
    }
}

// ---------- fused attention v7: v6 structure, min_waves=2 (no 64-VGPR clamp)
// grid (6, 12, 8), 256 threads (4 waves). Wave w owns i-tile w.
// s[i,j] = (q_i.k_j + q_i.Kp[t] + Qp[t].k_j)*0.125, t = j-i+383.
// NOTE: __launch_bounds__ min_waves>=4 empirically clamps VGPR to 64 on this
// toolchain (r8/r9 spill: WRITE_SIZE 206/22 MB). min_waves=2 -> no clamp.
__global__ __launch_bounds__(256, 2) void attn_fused7(
    const ushort* __restrict__ qk, const ushort* __restrict__ vT,
    const ushort* __restrict__ posKQ, ushort* __restrict__ aob)
{
    __shared__ ushort ccpt[2][64 * 72];   // c2c scores / P (aliased), double-buffered
    __shared__ ushort dqs[64 * 72];       // dq pre-shifted: dqs[i][j] = dq[i][j-i+63]
    __shared__ ushort dks[64 * 72];       // dk pre-shifted: dks[i][j] = dk[j-i+63][j]
    __shared__ float rowsum[64];

    const int tid = threadIdx.x;
    const int lane = tid & 63, w = tid >> 6;     // 4 waves; wave w = i-tile w
    const int i0 = blockIdx.x * 64;
    const int h = blockIdx.y, b = blockIdx.z;
    const int lm = lane & 15, lq = lane >> 4;
    const int exr = tid >> 2, exseg = tid & 3;   // 64 rows x 4 col-segments

    if (tid < 64) rowsum[tid] = 0.f;

    // q fragments: register-resident for the whole kernel
    short8 qf[2];
    {
        const ushort* qr = qk + (size_t)(b * SEQ + i0 + w * 16 + lm) * QKN + h * DH;
        qf[0] = *(const short8*)(qr + lq * 8);
        qf[1] = *(const short8*)(qr + 32 + lq * 8);
    }
    floatx4 occ[4] = {};

    for (int jt = 0; jt < 6; ++jt) {
        const int j0 = jt * 64;
        const int t0 = j0 - i0 + 320;    // t=127 row may overread into wsT pad (discarded)
        ushort* cc = ccpt[jt & 1];

        // k fragments for all 4 j-tiles (reused by dk and c2c)
        short8 kd[4][2];
#pragma unroll
        for (int s = 0; s < 4; ++s) {
            const ushort* kr = qk + (size_t)(b * SEQ + j0 + s * 16 + lm) * QKN + 768 + h * DH;
            kd[s][0] = *(const short8*)(kr + lq * 8);
            kd[s][1] = *(const short8*)(kr + 32 + lq * 8);
        }
        // dk: Qp-band @ k^T; wave w covers t-tiles {2w, 2w+1} x 4 j-tiles
#pragma unroll
        for (int tt = 0; tt < 2; ++tt) {
            int ttile = w * 2 + tt;
            short8 qp[2];
            const ushort* qpr = posKQ + (size_t)(t0 + ttile * 16 + lm) * PN + 768 + h * DH;
            qp[0] = *(const short8*)(qpr + lq * 8);
            qp[1] = *(const short8*)(qpr + 32 + lq * 8);
            floatx4 e[4] = {};
#pragma unroll
            for (int s = 0; s < 4; ++s) {
                e[s] = MFMA(qp[0], kd[s][0], e[s], 0, 0, 0);
                e[s] = MFMA(qp[1], kd[s][1], e[s], 0, 0, 0);
            }
#pragma unroll
            for (int s = 0; s < 4; ++s) {
                int j = s * 16 + lm;
#pragma unroll
                for (int r = 0; r < 4; ++r) {
                    int t = ttile * 16 + lq * 4 + r;
                    int i = j - t + 63;
                    if ((unsigned)i < 64u) dks[i * 72 + j] = f2bf(e[s][r]);
                }
            }
        }
        // c2c: q @ k^T (reuses kd); i-tile w x 4 j-tiles
        {
            floatx4 a[4] = {};
#pragma unroll
            for (int s = 0; s < 4; ++s) {
                a[s] = MFMA(qf[0], kd[s][0], a[s], 0, 0, 0);
                a[s] = MFMA(qf[1], kd[s][1], a[s], 0, 0, 0);
            }
#pragma unroll
            for (int s = 0; s < 4; ++s) {
                int j = s * 16 + lm;
#pragma unroll
                for (int r = 0; r < 4; ++r)
                    cc[(w * 16 + lq * 4 + r) * 72 + j] = f2bf(a[s][r]);
            }
        }
        // dq: q @ Kp-band^T; i-tile w x 8 t-tiles, kp streamed
#pragma unroll
        for (int s8 = 0; s8 < 8; ++s8) {
            short8 kp[2];
            const ushort* kpr = posKQ + (size_t)(t0 + s8 * 16 + lm) * PN + h * DH;
            kp[0] = *(const short8*)(kpr + lq * 8);
            kp[1] = *(const short8*)(kpr + 32 + lq * 8);
            floatx4 d = {};
            d = MFMA(qf[0], kp[0], d, 0, 0, 0);
            d = MFMA(qf[1], kp[1], d, 0, 0, 0);
            int t = s8 * 16 + lm;
#pragma unroll
            for (int r = 0; r < 4; ++r) {
                int i = w * 16 + lq * 4 + r;
                int j = t + i - 63;
                if ((unsigned)j < 64u) dqs[i * 72 + j] = f2bf(d[r]);
            }
        }
        __syncthreads();                                   // (1) scores complete

        // phase C: gather 3 terms (b128), exp, rowsum, P in-place
        {
            float psum = 0.f;
            ushort pv[16];
#pragma unroll
            for (int hh = 0; hh < 2; ++hh) {
                int off = exr * 72 + exseg * 16 + hh * 8;
                uint4 c4 = *(const uint4*)&cc[off];
                uint4 q4 = *(const uint4*)&dqs[off];
                uint4 k4 = *(const uint4*)&dks[off];
                const ushort* cu = (const ushort*)&c4;
                const ushort* qu = (const ushort*)&q4;
                const ushort* ku = (const ushort*)&k4;
#pragma unroll
                for (int c = 0; c < 8; ++c) {
                    float sv = (bf2f(cu[c]) + bf2f(qu[c]) + bf2f(ku[c])) * 0.125f;
                    float pe = __expf(sv);
                    psum += pe;
                    pv[hh * 8 + c] = f2bf(pe);
                }
            }
            psum += __shfl_xor(psum, 1);
            psum += __shfl_xor(psum, 2);
            if (exseg == 0) rowsum[exr] += psum;
#pragma unroll
            for (int hh = 0; hh < 2; ++hh)
                *(uint4*)&cc[exr * 72 + exseg * 16 + hh * 8] = *(uint4*)&pv[hh * 8];
        }
        __syncthreads();                                   // (2) pt visible

        // PV: i-tile w x 4 d-tiles, vf streamed; overlaps next iter safely
        // (next iter writes the OTHER cc buffer; dqs/dks writes occur only
        //  after all waves pass barrier (2))
#pragma unroll
        for (int dt = 0; dt < 4; ++dt) {
            short8 vf[2];
            const ushort* vr = vT + ((size_t)(b * NH + h) * DH + dt * 16 + lm) * SEQ + j0;
            vf[0] = *(const short8*)(vr + lq * 8);
            vf[1] = *(const short8*)(vr + 32 + lq * 8);
#pragma unroll
            for (int kk = 0; kk < 2; ++kk) {
                short8 af = *(const short8*)&cc[(w * 16 + lm) * 72 + kk * 32 + lq * 8];
                occ[dt] = MFMA(af, vf[kk], occ[dt], 0, 0, 0);
            }
        }
    }

#pragma unroll
    for (int dt = 0; dt < 4; ++dt) {
#pragma unroll
        for (int r = 0; r < 4; ++r) {
            int row = w * 16 + lq * 4 + r;
            float ov = occ[dt][r] / rowsum[row];
            aob[(size_t)(b * SEQ + i0 + row) * DIM + h * DH + dt * 16 + lm] = f2bf(ov);
        }
    }
}

extern "C" void kernel_launch(void* const* d_in, const int* in_sizes, int n_in,
                              void* d_out, int out_size, void* d_ws, size_t ws_size,
                              hipStream_t stream) {
    const float* x   = (const float*)d_in[0];
    const float* rpe = (const float*)d_in[1];
    const float* Wq  = (const float*)d_in[2];
    const float* bq  = (const float*)d_in[3];
    const float* Wk  = (const float*)d_in[4];
    const float* bk  = (const float*)d_in[5];
    const float* Wv  = (const float*)d_in[6];
    const float* bv  = (const float*)d_in[7];
    const float* qbias = (const float*)d_in[8];
    const float* vbias = (const float*)d_in[9];
    const float* Wpk = (const float*)d_in[10];
    const float* Wpq = (const float*)d_in[11];
    const float* Wo  = (const float*)d_in[12];
    const float* bo  = (const float*)d_in[13];
    float* out = (float*)d_out;

    char* ws = (char*)d_ws;
    ushort* xb    = (ushort*)ws; ws += (size_t)NTOK * DIM * 2;
    ushort* qkbuf = (ushort*)ws; ws += (size_t)NTOK * QKN * 2;
    ushort* vT    = (ushort*)ws; ws += (size_t)NTOK * DIM * 2;
    ushort* aob   = (ushort*)ws; ws += (size_t)NTOK * DIM * 2;
    ushort* rpeb  = (ushort*)ws; ws += (size_t)NPOS * DIM * 2;
    ushort* posKQ = (ushort*)ws; ws += (size_t)NPOS * PN * 2;
    ushort* wsT   = (ushort*)ws; ws += (size_t)6 * DIM * DIM * 2;   // must follow posKQ (t=767 overread pad)

    // 1) converts + weight transposes
    prep<<<dim3(12, 12, 7), dim3(256), 0, stream>>>(
        Wq, Wk, Wv, Wpk, Wpq, Wo, x, rpe, wsT, xb, rpeb);
    // 2) QKV projection + positional projections in one launch (504 blocks)
    proj_all<<<dim3(504), dim3(256), 0, stream>>>(
        xb, rpeb, wsT, bq, qbias, bk, bv, vbias, qkbuf, vT, posKQ);
    // 3) fused attention (register-direct fragments, no VGPR clamp)
    attn_fused7<<<dim3(SEQ / 64, NH, BATCH), dim3(256), 0, stream>>>(qkbuf, vT, posKQ, aob);
    // 4) output projection -> fp32 d_out (288 blocks)
    gemm128x64<<<dim3(DIM / 64, NTOK / 128), dim3(256), 0, stream>>>(
        aob, wsT + (size_t)5 * DIM * DIM, bo, out, NTOK, DIM, DIM);
}

// Round 11
// 183.204 us; speedup vs baseline: 1.4838x; 1.1540x over previous
//
#include <hip/hip_runtime.h>
#include <hip/hip_bf16.h>
#include <math.h>

#define BATCH 8
#define SEQ 384
#define DIM 768
#define NH 12
#define DH 64
#define NPOS 767
#define POS_OFF 128
#define NTOK (BATCH * SEQ)
#define QKN 1536
#define QKVN 2304
#define PN 1536

typedef __attribute__((ext_vector_type(8))) short short8;
typedef __attribute__((ext_vector_type(4))) float floatx4;
typedef unsigned int u32;

__device__ __forceinline__ ushort f2bf(float f) {
    __hip_bfloat16 h = __float2bfloat16(f);
    return *reinterpret_cast<ushort*>(&h);
}
__device__ __forceinline__ float bf2f(ushort u) {
    u32 x = ((u32)u) << 16;
    float f; __builtin_memcpy(&f, &x, 4); return f;
}

// async global->LDS, 16B per lane; lds dest = wave-uniform base + lane*16
__device__ __forceinline__ void gld16(const ushort* g, ushort* l) {
    __builtin_amdgcn_global_load_lds(
        (const __attribute__((address_space(1))) u32*)g,
        (__attribute__((address_space(3))) u32*)l, 16, 0, 0);
}

#define MFMA __builtin_amdgcn_mfma_f32_16x16x32_bf16

// ---------- prep: weight transposes (z<6) + row converts (z==6) -----------
__global__ __launch_bounds__(256) void prep(
    const float* W0, const float* W1, const float* W2,
    const float* W3, const float* W4, const float* W5,
    const float* x, const float* rpe,
    ushort* __restrict__ wsT, ushort* __restrict__ xb, ushort* __restrict__ rpeb)
{
    const int tid = threadIdx.x;
    if (blockIdx.z < 6) {
        __shared__ float t[64][65];
        const float* srcs[6] = {W0, W1, W2, W3, W4, W5};
        const float* in = srcs[blockIdx.z];
        ushort* out = wsT + (size_t)blockIdx.z * DIM * DIM;
        const int r0 = blockIdx.y * 64, c0 = blockIdx.x * 64;
        for (int p = 0; p < 16; ++p) {
            int e = tid + p * 256, i = e >> 6, j = e & 63;
            t[i][j] = in[(size_t)(r0 + i) * DIM + c0 + j];
        }
        __syncthreads();
        for (int p = 0; p < 16; ++p) {
            int e = tid + p * 256, i = e >> 6, j = e & 63;
            out[(size_t)(c0 + i) * DIM + r0 + j] = f2bf(t[j][i]);
        }
    } else {
        const int n4x = NTOK * DIM / 4;
        const int n4p = NPOS * DIM / 4;
        const int fb = blockIdx.y * 12 + blockIdx.x;      // 0..143
        for (int idx = fb * 256 + tid; idx < n4x + n4p; idx += 144 * 256) {
            const float* src; ushort* dst; int j;
            if (idx < n4x) { src = x; dst = xb; j = idx; }
            else { src = rpe + (size_t)POS_OFF * DIM; dst = rpeb; j = idx - n4x; }
            float4 f = ((const float4*)src)[j];
            ushort o[4] = {f2bf(f.x), f2bf(f.y), f2bf(f.z), f2bf(f.w)};
            *(uint2*)&dst[(size_t)j * 4] = *(uint2*)o;
        }
    }
}

// ---------- combined projections: QKV (blocks 0..431) + pos (432..503) ----
__global__ __launch_bounds__(256) void proj_all(
    const ushort* __restrict__ xb, const ushort* __restrict__ rpeb,
    const ushort* __restrict__ wsT,
    const float* __restrict__ bq, const float* __restrict__ qbias,
    const float* __restrict__ bk, const float* __restrict__ bv,
    const float* __restrict__ vbias,
    ushort* __restrict__ qk, ushort* __restrict__ vT, ushort* __restrict__ posKQ)
{
    __shared__ ushort As[128 * 64];
    __shared__ ushort Bs[128 * 64];
    const int tid = threadIdx.x;
    const int lane = tid & 63, w = tid >> 6;
    const int id = blockIdx.x;
    const bool qkvP = id < 432;
    const ushort* A; const ushort* Bt; int m0, n0, M;
    if (qkvP) {
        m0 = (id % 24) * 128; n0 = (id / 24) * 128;
        A = xb; Bt = wsT; M = NTOK;
    } else {
        int p = id - 432;
        m0 = (p % 6) * 128; n0 = (p / 6) * 128;
        A = rpeb; Bt = wsT + (size_t)3 * DIM * DIM; M = NPOS;
    }
    const int lr = lane >> 3;
    const int lc = (lane & 7) ^ (lr & 7);
    const ushort* ga[4]; const ushort* gb[4];
#pragma unroll
    for (int p = 0; p < 4; ++p) {
        int row = (w * 4 + p) * 8 + lr;
        int arow = m0 + row; if (arow > M - 1) arow = M - 1;
        ga[p] = A + (size_t)arow * DIM + lc * 8;
        gb[p] = Bt + (size_t)(n0 + row) * DIM + lc * 8;
    }
    floatx4 acc[4][4] = {};
    const int qr = (w >> 1) * 64, qc = (w & 1) * 64;
    const int lm = lane & 15, lk = lane >> 4;
    for (int k0 = 0; k0 < DIM; k0 += 64) {
#pragma unroll
        for (int p = 0; p < 4; ++p) {
            gld16(ga[p], As + (w * 4 + p) * 512);
            gld16(gb[p], Bs + (w * 4 + p) * 512);
            ga[p] += 64; gb[p] += 64;
        }
        __syncthreads();
#pragma unroll
        for (int kk = 0; kk < 2; ++kk) {
            int ch = (kk * 4 + lk) ^ (lm & 7);
            short8 af[4], bf[4];
#pragma unroll
            for (int t = 0; t < 4; ++t) {
                af[t] = *(const short8*)&As[(qr + t * 16 + lm) * 64 + ch * 8];
                bf[t] = *(const short8*)&Bs[(qc + t * 16 + lm) * 64 + ch * 8];
            }
#pragma unroll
            for (int i = 0; i < 4; ++i)
#pragma unroll
                for (int j = 0; j < 4; ++j)
                    acc[i][j] = MFMA(af[i], bf[j], acc[i][j], 0, 0, 0);
        }
        __syncthreads();
    }
    if (qkvP) {
#pragma unroll
        for (int i = 0; i < 4; ++i) {
            int mbase = m0 + qr + i * 16 + (lane >> 4) * 4;
            int bb = mbase / SEQ;
            int s0 = mbase - bb * SEQ;
#pragma unroll
            for (int j = 0; j < 4; ++j) {
                int n = n0 + qc + j * 16 + lm;
                float bs;
                if (n < 768) bs = bq[n] + qbias[n];
                else if (n < QKN) bs = bk[n - 768];
                else bs = bv[n - QKN] + vbias[n - QKN];
                if (n < QKN) {
#pragma unroll
                    for (int r = 0; r < 4; ++r)
                        qk[(size_t)(mbase + r) * QKN + n] = f2bf(acc[i][j][r] + bs);
                } else {
                    int c = n - QKN, h = c >> 6, d = c & 63;
                    ushort tmp[4];
#pragma unroll
                    for (int r = 0; r < 4; ++r) tmp[r] = f2bf(acc[i][j][r] + bs);
                    *(uint2*)&vT[(((size_t)bb * NH + h) * DH + d) * SEQ + s0] = *(uint2*)tmp;
                }
            }
        }
    } else {
#pragma unroll
        for (int i = 0; i < 4; ++i) {
            int mbase = m0 + qr + i * 16 + (lane >> 4) * 4;
#pragma unroll
            for (int j = 0; j < 4; ++j) {
                int n = n0 + qc + j * 16 + lm;
#pragma unroll
                for (int r = 0; r < 4; ++r) {
                    int row = mbase + r;
                    if (row < NPOS)
                        posKQ[(size_t)row * PN + n] = f2bf(acc[i][j][r]);
                }
            }
        }
    }
}

// ---------- 128x64-tile MFMA GEMM (output projection, 288 blocks) ---------
__global__ __launch_bounds__(256) void gemm128x64(
    const ushort* __restrict__ A, const ushort* __restrict__ Bt,
    const float* __restrict__ bias, float* __restrict__ outF,
    int M, int N, int K)
{
    __shared__ ushort As[128 * 64];
    __shared__ ushort Bs[64 * 64];
    const int tid = threadIdx.x;
    const int lane = tid & 63, w = tid >> 6;
    const int n0 = blockIdx.x * 64, m0 = blockIdx.y * 128;
    const int lr = lane >> 3;
    const int lc = (lane & 7) ^ (lr & 7);
    const ushort* ga[4]; const ushort* gb[2];
#pragma unroll
    for (int p = 0; p < 4; ++p) {
        int arow = m0 + (w * 4 + p) * 8 + lr; if (arow > M - 1) arow = M - 1;
        ga[p] = A + (size_t)arow * K + lc * 8;
    }
#pragma unroll
    for (int p = 0; p < 2; ++p)
        gb[p] = Bt + (size_t)(n0 + (w * 2 + p) * 8 + lr) * K + lc * 8;
    floatx4 acc[4][2] = {};
    const int qr = (w >> 1) * 64, qc = (w & 1) * 32;
    const int lm = lane & 15, lk = lane >> 4;
    for (int k0 = 0; k0 < K; k0 += 64) {
#pragma unroll
        for (int p = 0; p < 4; ++p) { gld16(ga[p], As + (w * 4 + p) * 512); ga[p] += 64; }
#pragma unroll
        for (int p = 0; p < 2; ++p) { gld16(gb[p], Bs + (w * 2 + p) * 512); gb[p] += 64; }
        __syncthreads();
#pragma unroll
        for (int kk = 0; kk < 2; ++kk) {
            int ch = (kk * 4 + lk) ^ (lm & 7);
            short8 af[4], bf[2];
#pragma unroll
            for (int t = 0; t < 4; ++t)
                af[t] = *(const short8*)&As[(qr + t * 16 + lm) * 64 + ch * 8];
#pragma unroll
            for (int t = 0; t < 2; ++t)
                bf[t] = *(const short8*)&Bs[(qc + t * 16 + lm) * 64 + ch * 8];
#pragma unroll
            for (int i = 0; i < 4; ++i)
#pragma unroll
                for (int j = 0; j < 2; ++j)
                    acc[i][j] = MFMA(af[i], bf[j], acc[i][j], 0, 0, 0);
        }
        __syncthreads();
    }
#pragma unroll
    for (int i = 0; i < 4; ++i) {
        int mbase = m0 + qr + i * 16 + (lane >> 4) * 4;
#pragma unroll
        for (int j = 0; j < 2; ++j) {
            int n = n0 + qc + j * 16 + lm;
            float bs = bias[n];
#pragma unroll
            for (int r = 0; r < 4; ++r) {
                int row = mbase + r;
                if (row < M) outF[(size_t)row * N + n] = acc[i][j][r] + bs;
            }
        }
    }
}

// ---------- fused attention v8: gld16 staging + bf16 buffers, 3 barriers --
// grid (6, 12, 8), 512 threads (8 waves). 2 blocks/CU (76 KB LDS).
// s[i,j] = (q_i.k_j + q_i.Kp[t] + Qp[t].k_j)*0.125, t = j-i+383.
// Staging for iter n+1 issues after barrier 2 (kt/kps/qps dead post-B),
// overlapping the DMA with phases C and D.
__global__ __launch_bounds__(512, 2) void attn_fused8(
    const ushort* __restrict__ qk, const ushort* __restrict__ vT,
    const ushort* __restrict__ posKQ, ushort* __restrict__ aob)
{
    __shared__ ushort kt[64 * 64];        // 8 KB  k tile (swizzled)
    __shared__ ushort kps[128 * 64];      // 16 KB Kp band
    __shared__ ushort qps[128 * 64];      // 16 KB Qp band
    __shared__ ushort ccpt[2][64 * 72];   // 18 KB c2c scores / P (in-place), dbuf
    __shared__ ushort dqs[64 * 72];       // 9 KB  dq pre-shifted: [i][j]=dq[i][j-i+63]
    __shared__ ushort dks[64 * 72];       // 9 KB  dk pre-shifted: [i][j]=dk[j-i+63][j]
    __shared__ float rowsum[64];

    const int tid = threadIdx.x;
    const int lane = tid & 63, w = tid >> 6;
    const int i0 = blockIdx.x * 64;
    const int h = blockIdx.y, b = blockIdx.z;
    const int lm = lane & 15, lq = lane >> 4;
    const int lr = lane >> 3, l8 = lane & 7;
    const int lc = l8 ^ (lr & 7);                 // swizzled source chunk
    const int exr = tid >> 3, exseg = tid & 7;    // 64 rows x 8 segs (phase C)

    if (tid < 64) rowsum[tid] = 0.f;

    // q fragments: register-resident (i-tile w>>1; two waves share a tile)
    short8 qf[2];
    {
        const ushort* qr = qk + (size_t)(b * SEQ + i0 + (w >> 1) * 16 + lm) * QKN + h * DH;
        qf[0] = *(const short8*)(qr + lq * 8);
        qf[1] = *(const short8*)(qr + 32 + lq * 8);
    }
    const ushort* kb = qk + 768 + h * DH;
    floatx4 occ[2] = {};

    // stage j-tile 0
    {
        int t0 = 0 - i0 + 320;
        gld16(kb + (size_t)(b * SEQ + 8 * w + lr) * QKN + lc * 8, kt + w * 512);
        gld16(posKQ + (size_t)(t0 + 16 * w + lr) * PN + h * DH + lc * 8, kps + w * 1024);
        gld16(posKQ + (size_t)(t0 + 16 * w + 8 + lr) * PN + h * DH + lc * 8, kps + w * 1024 + 512);
        gld16(posKQ + (size_t)(t0 + 16 * w + lr) * PN + 768 + h * DH + lc * 8, qps + w * 1024);
        gld16(posKQ + (size_t)(t0 + 16 * w + 8 + lr) * PN + 768 + h * DH + lc * 8, qps + w * 1024 + 512);
    }

    for (int jt = 0; jt < 6; ++jt) {
        const int j0 = jt * 64;
        ushort* cc = ccpt[jt & 1];
        __syncthreads();        // (1) staging landed; prev C (dqs/dks) + PV (other cc) done

        // ---- phase B: c2c + dq + dk -> bf16 buffers, unique writers ----
        { // c2c: i-tile w>>1 x j-tiles (w&1)*2+{0,1}
            int tr = w >> 1, tcb = (w & 1) * 2;
            floatx4 a[2] = {};
#pragma unroll
            for (int kk = 0; kk < 2; ++kk) {
                int ch = (kk * 4 + lq) ^ (lm & 7);
                short8 b0 = *(const short8*)&kt[(tcb * 16 + lm) * 64 + ch * 8];
                short8 b1 = *(const short8*)&kt[((tcb + 1) * 16 + lm) * 64 + ch * 8];
                a[0] = MFMA(qf[kk], b0, a[0], 0, 0, 0);
                a[1] = MFMA(qf[kk], b1, a[1], 0, 0, 0);
            }
#pragma unroll
            for (int s = 0; s < 2; ++s) {
                int j = (tcb + s) * 16 + lm;
#pragma unroll
                for (int r = 0; r < 4; ++r)
                    cc[(tr * 16 + lq * 4 + r) * 72 + j] = f2bf(a[s][r]);
            }
        }
        { // dq: i-tile w>>1 x t-tiles (w&1)*4+{0..3}, diag pre-shift store
            int tr = w >> 1, tcb = (w & 1) * 4;
            floatx4 d[4] = {};
#pragma unroll
            for (int kk = 0; kk < 2; ++kk) {
                int ch = (kk * 4 + lq) ^ (lm & 7);
#pragma unroll
                for (int s = 0; s < 4; ++s) {
                    short8 bf = *(const short8*)&kps[((tcb + s) * 16 + lm) * 64 + ch * 8];
                    d[s] = MFMA(qf[kk], bf, d[s], 0, 0, 0);
                }
            }
#pragma unroll
            for (int s = 0; s < 4; ++s) {
                int t = (tcb + s) * 16 + lm;
#pragma unroll
                for (int r = 0; r < 4; ++r) {
                    int i = tr * 16 + lq * 4 + r;
                    int j = t + i - 63;
                    if ((unsigned)j < 64u) dqs[i * 72 + j] = f2bf(d[s][r]);
                }
            }
        }
        { // dk: t-tile w x j-tiles {0..3}, diag pre-shift store
            floatx4 e[4] = {};
#pragma unroll
            for (int kk = 0; kk < 2; ++kk) {
                int ch = (kk * 4 + lq) ^ (lm & 7);
                short8 af = *(const short8*)&qps[(w * 16 + lm) * 64 + ch * 8];
#pragma unroll
                for (int s = 0; s < 4; ++s) {
                    short8 bf = *(const short8*)&kt[(s * 16 + lm) * 64 + ch * 8];
                    e[s] = MFMA(af, bf, e[s], 0, 0, 0);
                }
            }
#pragma unroll
            for (int s = 0; s < 4; ++s) {
                int j = s * 16 + lm;
#pragma unroll
                for (int r = 0; r < 4; ++r) {
                    int t = w * 16 + lq * 4 + r;
                    int i = j - t + 63;
                    if ((unsigned)i < 64u) dks[i * 72 + j] = f2bf(e[s][r]);
                }
            }
        }
        __syncthreads();        // (2) B done; kt/kps/qps free

        // issue next iter's staging (overlaps phases C and D)
        if (jt < 5) {
            int j0n = j0 + 64;
            int t0n = j0n - i0 + 320;       // t=127 row may overread into wsT pad
            gld16(kb + (size_t)(b * SEQ + j0n + 8 * w + lr) * QKN + lc * 8, kt + w * 512);
            gld16(posKQ + (size_t)(t0n + 16 * w + lr) * PN + h * DH + lc * 8, kps + w * 1024);
            gld16(posKQ + (size_t)(t0n + 16 * w + 8 + lr) * PN + h * DH + lc * 8, kps + w * 1024 + 512);
            gld16(posKQ + (size_t)(t0n + 16 * w + lr) * PN + 768 + h * DH + lc * 8, qps + w * 1024);
            gld16(posKQ + (size_t)(t0n + 16 * w + 8 + lr) * PN + 768 + h * DH + lc * 8, qps + w * 1024 + 512);
        }

        // ---- phase C: gather 3 terms (b128), exp, rowsum, P in place ----
        {
            int off = exr * 72 + exseg * 8;
            uint4 c4 = *(const uint4*)&cc[off];
            uint4 q4 = *(const uint4*)&dqs[off];
            uint4 k4 = *(const uint4*)&dks[off];
            const ushort* cu = (const ushort*)&c4;
            const ushort* qu = (const ushort*)&q4;
            const ushort* ku = (const ushort*)&k4;
            float psum = 0.f;
            ushort pv[8];
#pragma unroll
            for (int c = 0; c < 8; ++c) {
                float sv = (bf2f(cu[c]) + bf2f(qu[c]) + bf2f(ku[c])) * 0.125f;
                float pe = __expf(sv);
                psum += pe;
                pv[c] = f2bf(pe);
            }
            psum += __shfl_xor(psum, 1);
            psum += __shfl_xor(psum, 2);
            psum += __shfl_xor(psum, 4);
            if (exseg == 0) rowsum[exr] += psum;
            *(uint4*)&cc[off] = *(uint4*)pv;
        }
        __syncthreads();        // (3) P visible

        // ---- phase D: PV accumulate; v direct-to-register -------------
        {
            int tr = w >> 1, dtb = (w & 1) * 2;
#pragma unroll
            for (int t2 = 0; t2 < 2; ++t2) {
                int dt = dtb + t2;
                const ushort* vr = vT + ((size_t)(b * NH + h) * DH + dt * 16 + lm) * SEQ + j0;
                short8 vf0 = *(const short8*)(vr + lq * 8);
                short8 vf1 = *(const short8*)(vr + 32 + lq * 8);
                short8 af0 = *(const short8*)&cc[(tr * 16 + lm) * 72 + lq * 8];
                short8 af1 = *(const short8*)&cc[(tr * 16 + lm) * 72 + 32 + lq * 8];
                occ[t2] = MFMA(af0, vf0, occ[t2], 0, 0, 0);
                occ[t2] = MFMA(af1, vf1, occ[t2], 0, 0, 0);
            }
        }
        // no barrier: next iter's (1) protects cc (other buffer) and dqs/dks
    }

    {
        int tr = w >> 1, dtb = (w & 1) * 2;
#pragma unroll
        for (int t2 = 0; t2 < 2; ++t2) {
#pragma unroll
            for (int r = 0; r < 4; ++r) {
                int row = tr * 16 + lq * 4 + r;
                float ov = occ[t2][r] / rowsum[row];
                aob[(size_t)(b * SEQ + i0 + row) * DIM + h * DH + (dtb + t2) * 16 + lm] = f2bf(ov);
            }
        }
    }
}

extern "C" void kernel_launch(void* const* d_in, const int* in_sizes, int n_in,
                              void* d_out, int out_size, void* d_ws, size_t ws_size,
                              hipStream_t stream) {
    const float* x   = (const float*)d_in[0];
    const float* rpe = (const float*)d_in[1];
    const float* Wq  = (const float*)d_in[2];
    const float* bq  = (const float*)d_in[3];
    const float* Wk  = (const float*)d_in[4];
    const float* bk  = (const float*)d_in[5];
    const float* Wv  = (const float*)d_in[6];
    const float* bv  = (const float*)d_in[7];
    const float* qbias = (const float*)d_in[8];
    const float* vbias = (const float*)d_in[9];
    const float* Wpk = (const float*)d_in[10];
    const float* Wpq = (const float*)d_in[11];
    const float* Wo  = (const float*)d_in[12];
    const float* bo  = (const float*)d_in[13];
    float* out = (float*)d_out;

    char* ws = (char*)d_ws;
    ushort* xb    = (ushort*)ws; ws += (size_t)NTOK * DIM * 2;
    ushort* qkbuf = (ushort*)ws; ws += (size_t)NTOK * QKN * 2;
    ushort* vT    = (ushort*)ws; ws += (size_t)NTOK * DIM * 2;
    ushort* aob   = (ushort*)ws; ws += (size_t)NTOK * DIM * 2;
    ushort* rpeb  = (ushort*)ws; ws += (size_t)NPOS * DIM * 2;
    ushort* posKQ = (ushort*)ws; ws += (size_t)NPOS * PN * 2;
    ushort* wsT   = (ushort*)ws; ws += (size_t)6 * DIM * DIM * 2;   // must follow posKQ (t=767 overread pad)

    // 1) converts + weight transposes
    prep<<<dim3(12, 12, 7), dim3(256), 0, stream>>>(
        Wq, Wk, Wv, Wpk, Wpq, Wo, x, rpe, wsT, xb, rpeb);
    // 2) QKV projection + positional projections in one launch (504 blocks)
    proj_all<<<dim3(504), dim3(256), 0, stream>>>(
        xb, rpeb, wsT, bq, qbias, bk, bv, vbias, qkbuf, vT, posKQ);
    // 3) fused attention (staged + bf16 buffers, 2 blocks/CU, 3 barriers/iter)
    attn_fused8<<<dim3(SEQ / 64, NH, BATCH), dim3(512), 0, stream>>>(qkbuf, vT, posKQ, aob);
    // 4) output projection -> fp32 d_out (288 blocks)
    gemm128x64<<<dim3(DIM / 64, NTOK / 128), dim3(256), 0, stream>>>(
        aob, wsT + (size_t)5 * DIM * DIM, bo, out, NTOK, DIM, DIM);
}